// Round 7
// baseline (392.849 us; speedup 1.0000x reference)
//
#include <hip/hip_runtime.h>

// x: [16,128,128,128] fp32 ; pixel_shuffle(2) -> [16,32,256,256]
// 4x4 separable FIR (outer([1,3,3,1])/64), pad=2 -> out [16,32,257,257]
//
// R9: bisect the write-amplification variable. Evidence table:
//   R0-R4: 32B-strided scalar stores, 17-33 strips/plane, 8 blk/CU -> WRITE 137MB (clean)
//   R5/R6: contiguous stores, 4 strips/plane, 8 streams/CU        -> WRITE 133MB (clean)
//   R7:    strided stores,   16 strips/plane, 32 streams/CU       -> WRITE 237MB (1.81x)
//   R8:    contiguous stores,16 strips/plane, 32 streams/CU       -> WRITE 239MB (1.81x)
// => store instruction pattern is irrelevant (R8 null); amplification
// correlates with concurrent write-stream count / strip geometry. Candidate
// mechanism: at 15K cy/wave-iter (95% stalled) x 32 streams/CU, freshly
// written row-lines are evicted from the 4MB XCD L2 before the adjacent
// row merges -> refetch + double TCC->EA write.
// R9 = R8 with ONLY strip geometry reverted to R5's: TY 65, NSTRIP 4,
// grid(512,1) -> 2048 waves, 8 streams/CU, 2 waves/SIMD. Occupancy 25% is
// deliberate: R4 proved occupancy isn't binding; depth-2 reg prefetch
// covers ~3K cy >> 900 cy HBM latency at roof pacing. If traffic cleans
// up (~205MB) at the demonstrated ~2.9 TB/s mixed roof -> ~70-90us.
constexpr int Hn = 128;
constexpr int Wn = 128;
constexpr int SH = 2 * Hn;   // 256 shuffled rows
constexpr int OH = SH + 1;   // 257
constexpr int OW = 257;
constexpr int HW = Hn * Wn;  // input plane stride
constexpr int TY = 65;       // output rows per wave
constexpr int NSTRIP = 4;    // 4*65 = 260 >= 257
constexpr int NBC = 16 * 32; // 512 (b,c) planes
constexpr int NIT = TY + 3;  // 68 staged shuffled rows per strip (even)

__global__ __launch_bounds__(256, 8) void upsamp_fir_wavet65(
    const float* __restrict__ x,
    const float* __restrict__ k4,
    float* __restrict__ out)
{
    const int tix   = threadIdx.x;
    const int lane  = tix & 63;
    const int wid   = tix >> 6;
    const int bc    = blockIdx.x;
    const int strip = wid;               // NSTRIP==4, one block spans them
    const int oh0   = strip * TY;

    const float* xp = x + (size_t)bc * 4 * HW;

    // Per-wave transpose buffer (no cross-wave sharing -> no barriers).
    __shared__ __align__(16) float tbuf[4][256];
    float* const trow = tbuf[wid];

    // Separable taps (flipped for true convolution), exact for this kernel.
    float fh[4], fv[4];
#pragma unroll
    for (int j = 0; j < 4; ++j) fh[j] = k4[j] + k4[4+j] + k4[8+j] + k4[12+j];
#pragma unroll
    for (int i = 0; i < 4; ++i) fv[i] = k4[4*i] + k4[4*i+1] + k4[4*i+2] + k4[4*i+3];
    const float h0 = fh[3], h1 = fh[2], h2 = fh[1], h3 = fh[0];
    const float g0 = fv[3], g1 = fv[2], g2 = fv[1], g3 = fv[0];

    const bool l0  = (lane == 0);
    const bool l63 = (lane == 63);
    const int  colOff = 2 * lane;              // input col of E2.x / O2.x

    // Load shuffled row s: E pair (even out-cols 4m,4m+2 = input cols
    // 2m,2m+1 of plane 2*(s&1)) and O pair (odd cols, plane 2*(s&1)+1).
    auto loadrow = [&](int s, float2& e2, float2& o2) {
        if ((unsigned)s >= (unsigned)SH) {
            e2 = make_float2(0.f, 0.f); o2 = e2; return;
        }
        const float* be = xp + (size_t)((s & 1) * 2) * HW
                             + (size_t)(s >> 1) * Wn + colOff;
        e2 = *(const float2*)be;
        o2 = *(const float2*)(be + HW);
    };

    float2 eA, oA, eB, oB;
    loadrow(oh0 - 2, eA, oA);
    loadrow(oh0 - 1, eB, oB);

    // Rolling horizontal results for the 4 owned cols + edge col 256.
    float m30=0,m31=0,m32=0,m33=0;   // H(s-3)
    float m20=0,m21=0,m22=0,m23=0;   // H(s-2)
    float m10=0,m11=0,m12=0,m13=0;   // H(s-1)
    float e3=0, e2r=0, e1r=0;        // edge col rolling

    float* const obase = out + (size_t)bc * OH * OW;

    auto step = [&](int i, float2& E2, float2& O2) {
        const int s = oh0 - 2 + i;
        const float Ex = E2.x, Ey = E2.y, Ox = O2.x, Oy = O2.y;
        // Cross-lane neighbors (wave edge = global zero-pad).
        float Em1 = __shfl_up(Ey, 1);   Em1 = l0  ? 0.f : Em1;  // E[2m-1]
        float Om1 = __shfl_up(Oy, 1);   Om1 = l0  ? 0.f : Om1;  // O[2m-1]
        float Ep1 = __shfl_down(Ex, 1); Ep1 = l63 ? 0.f : Ep1;  // E[2m+2]
        // Horizontal FIR, out cols 4m..4m+3 (+ col 256 in lane 63).
        const float H0 = h0*Em1 + h1*Om1 + h2*Ex + h3*Ox;
        const float H1 = h0*Om1 + h1*Ex  + h2*Ox + h3*Ey;
        const float H2 = h0*Ex  + h1*Ox  + h2*Ey + h3*Oy;
        const float H3 = h0*Ox  + h1*Ey  + h2*Oy + h3*Ep1;
        const float H4 = h0*Ey  + h1*Oy;                    // col 256
        // Prefetch row s+2 into this buffer (consumed 2 steps later);
        // vmcnt is independent of the lgkm transpose waits below.
        if (i + 2 < NIT) loadrow(s + 2, E2, O2);
        // Emit output row oh = s-1 (needs H rows s-3..s).
        if (i >= 3) {
            const int oh = oh0 + i - 3;
            if (oh < OH) {
                float4 o4;
                o4.x = g0*m30 + g1*m20 + g2*m10 + g3*H0;
                o4.y = g0*m31 + g1*m21 + g2*m11 + g3*H1;
                o4.z = g0*m32 + g1*m22 + g2*m12 + g3*H2;
                o4.w = g0*m33 + g1*m23 + g2*m13 + g3*H3;
                const float oe = g0*e3 + g1*e2r + g2*e1r + g3*H4; // col 256
                // Wave-private transpose: strided-per-lane -> lane-contiguous.
                *(float4*)(trow + 4 * lane) = o4;      // ds_write_b128
                const float s0 = trow[lane];           // compiler lgkmcnt
                const float s1 = trow[lane + 64];
                const float s2 = trow[lane + 128];
                const float s3 = trow[lane + 192];
                float* pr = obase + (size_t)oh * OW;
                pr[lane]       = s0;   // 256B contiguous per store instr
                pr[lane + 64]  = s1;
                pr[lane + 128] = s2;
                pr[lane + 192] = s3;
                if (l63) pr[256] = oe;
            }
        }
        // Roll.
        m30=m20; m31=m21; m32=m22; m33=m23;
        m20=m10; m21=m11; m22=m12; m23=m13;
        m10=H0;  m11=H1;  m12=H2;  m13=H3;
        e3=e2r;  e2r=e1r; e1r=H4;
    };

#pragma unroll 2
    for (int i = 0; i < NIT; i += 2) {
        step(i,     eA, oA);
        step(i + 1, eB, oB);
    }
}

extern "C" void kernel_launch(void* const* d_in, const int* in_sizes, int n_in,
                              void* d_out, int out_size, void* d_ws, size_t ws_size,
                              hipStream_t stream)
{
    const float* x  = (const float*)d_in[0];
    const float* k4 = (const float*)d_in[1];
    float* out      = (float*)d_out;

    dim3 grid(NBC, 1, 1);   // 512 blocks; 4 waves = 4 strips of one plane
    upsamp_fir_wavet65<<<grid, dim3(256), 0, stream>>>(x, k4, out);
}

// Round 8
// 265.142 us; speedup vs baseline: 1.4817x; 1.4817x over previous
//
#include <hip/hip_runtime.h>

// x: [16,128,128,128] fp32 ; pixel_shuffle(2) -> [16,32,256,256]
// 4x4 separable FIR (outer([1,3,3,1])/64), pad=2 -> out [16,32,257,257]
//
// R10: R5's clean-write block-cooperative structure, amortized 4 rows/round.
// Evidence to date:
//   clean WRITE (133-137MB): R0-R4, R5/R6  — output rows written JOINTLY by
//     the block's waves in one tight episode (thread c owns col c).
//   dirty WRITE (218-239MB = 1.6-1.8x): R7/R8/R9 — wave-private whole-row
//     streams; independent of store instr shape (R8 null) and stream count
//     (R9: 8 streams still 1.62x). INVARIANT: block-coop row writes only.
//   R9 also showed Occ 20% (2 waves/SIMD) doesn't cover the chain: need >=
//     ~4 waves/SIMD.
// R5's residual cost: 68 rounds x ~2900cy wall vs ~1800cy accountable —
// overhead scales with round count (barrier + LDS round-trip + vmcnt FIFO
// chains). Fix: stage 4 shuffled rows per round (17 rounds): wave w loads
// row S+w as 2x float2 (512B/instr vs R5's 256B scalar), double-buffered
// LDS + 2 reg sets = full-round prefetch cover, lgkm-only barrier (R6-
// proven) keeps the prefetch & stores undrained. Per thread per round:
// 8x ds_read2 + ~60 VALU -> 4 outputs. Same LDS bytes/output as R5,
// 1/4 the barriers, 1/2 the load instrs.
// 512 bc x 4 strips = 2048 blocks = 8/CU, one residency round. LDS 8.25KB.
constexpr int Hn = 128;
constexpr int Wn = 128;
constexpr int SH = 2 * Hn;   // 256 shuffled rows
constexpr int OH = SH + 1;   // 257
constexpr int OW = 257;
constexpr int HW = Hn * Wn;  // input plane stride
constexpr int TY = 65;       // output rows per block-strip
constexpr int NSTRIP = 4;    // 4*65 = 260 >= 257
constexpr int NBC = 16 * 32; // 512 (b,c) planes
constexpr int NROUND = 17;   // 17 rounds x 4 staged rows = 68 = TY+3

// Barrier that does NOT drain vmem (R6-proven): LDS ordering only.
__device__ __forceinline__ void barrier_lgkm_only() {
    asm volatile("s_waitcnt lgkmcnt(0)\n\ts_barrier" ::: "memory");
}

__global__ __launch_bounds__(256, 8) void upsamp_fir_q4(
    const float* __restrict__ x,
    const float* __restrict__ k4,
    float* __restrict__ out)
{
    const int tix = threadIdx.x;
    const int bc  = blockIdx.x;
    const int oh0 = blockIdx.y * TY;
    const float* xp = x + (size_t)bc * 4 * HW;

    // Separable taps (flipped for true convolution), exact for this kernel.
    float fh[4], fv[4];
#pragma unroll
    for (int j = 0; j < 4; ++j) fh[j] = k4[j] + k4[4+j] + k4[8+j] + k4[12+j];
#pragma unroll
    for (int i = 0; i < 4; ++i) fv[i] = k4[4*i] + k4[4*i+1] + k4[4*i+2] + k4[4*i+3];
    const float t0 = fh[3], t1 = fh[2], t2 = fh[1], t3 = fh[0];
    const float g0 = fv[3], g1 = fv[2], g2 = fv[1], g3 = fv[0];

    // LDS: [buf][row j][E/O][132]. EB[1+m] = shuffled col 2m (m=0..127),
    // EB[0] = col -2 pad, EB[129] = col 256 pad (both zero). Same for OB
    // (cols odd). Staged rows j=0..3 of the round.
    __shared__ float lds[2][4][2][132];

    // Staging role: wave w loads row S+w; lane l loads dwords 2l,2l+1 of
    // the even plane (float2) and of the odd plane (float2).
    const int rsel = tix >> 6;
    const int l    = tix & 63;

    auto loadRows = [&](int S, float2& e2, float2& o2) {
        const int s = S + rsel;
        if ((unsigned)s >= (unsigned)SH) {
            e2 = make_float2(0.f, 0.f); o2 = e2; return;
        }
        const float* be = xp + (size_t)(2 * (s & 1)) * HW
                             + (size_t)(s >> 1) * Wn + 2 * l;
        e2 = *(const float2*)be;          // 8B-aligned
        o2 = *(const float2*)(be + HW);
    };
    auto stage = [&](int b, const float2& e2, const float2& o2) {
        float* EB = &lds[b][rsel][0][0];
        float* OB = &lds[b][rsel][1][0];
        EB[1 + 2*l] = e2.x; EB[2 + 2*l] = e2.y;   // indices 1..128
        OB[1 + 2*l] = o2.x; OB[2 + 2*l] = o2.y;
    };

    // Compute role: thread owns output col c = tix (thread 255 also col 256).
    const int c    = tix;
    const int mi   = c >> 1;
    const int codd = c & 1;
    const bool edge = (tix == 255);
    float* const obase = out + (size_t)bc * OH * OW;

    // Rolling vertical state: hp1=H(S-1), hp2=H(S-2), hp3=H(S-3); ep* for
    // col 256. Round 0's only valid output (j=3) uses N[] exclusively, so
    // zero-init is correct.
    float hp1 = 0, hp2 = 0, hp3 = 0;
    float ep1 = 0, ep2 = 0, ep3 = 0;

    auto computeRound = [&](int r, int b) {
        const int S = oh0 - 2 + 4 * r;
        float N[4], EN[4];
#pragma unroll
        for (int j = 0; j < 4; ++j) {
            const float* EB = &lds[b][j][0][0];
            const float* OB = &lds[b][j][1][0];
            // even c: p=EB[mi],EB[mi+1] q=OB[mi],OB[mi+1]
            // odd  c: p=OB[mi],OB[mi+1] q=EB[mi+1],EB[mi+2]
            const float* P = codd ? (OB + mi)     : (EB + mi);
            const float* Q = codd ? (EB + mi + 1) : (OB + mi);
            const float p0 = P[0], p1 = P[1];     // ds_read2_b32
            const float q0 = Q[0], q1 = Q[1];     // ds_read2_b32
            N[j]  = t0*p0 + t1*q0 + t2*p1 + t3*q1;
            EN[j] = t0*q0 + t1*p1;   // col 256 (valid in edge thread: q0=E[254], p1=O[255])
        }
#pragma unroll
        for (int j = 0; j < 4; ++j) {
            const int oh = S - 1 + j;
            if ((r > 0 || j == 3) && oh < OH) {
                float v, ve;
                if (j == 0) { v = g0*hp3 + g1*hp2 + g2*hp1 + g3*N[0];
                              ve = g0*ep3 + g1*ep2 + g2*ep1 + g3*EN[0]; }
                if (j == 1) { v = g0*hp2 + g1*hp1 + g2*N[0] + g3*N[1];
                              ve = g0*ep2 + g1*ep1 + g2*EN[0] + g3*EN[1]; }
                if (j == 2) { v = g0*hp1 + g1*N[0] + g2*N[1] + g3*N[2];
                              ve = g0*ep1 + g1*EN[0] + g2*EN[1] + g3*EN[2]; }
                if (j == 3) { v = g0*N[0] + g1*N[1] + g2*N[2] + g3*N[3];
                              ve = g0*EN[0] + g1*EN[1] + g2*EN[2] + g3*EN[3]; }
                float* p = obase + (size_t)oh * OW;
                p[c] = v;                       // block-coop: 256B/wave-instr
                if (edge) p[256] = ve;
            }
        }
        hp3 = N[1]; hp2 = N[2]; hp1 = N[3];
        ep3 = EN[1]; ep2 = EN[2]; ep1 = EN[3];
    };

    // Prologue: round 0 staged to buf0; pads zeroed; round 1 in regs.
    float2 eA, oA, eB, oB;
    loadRows(oh0 - 2, eA, oA);            // round 0 (S = oh0-2)
    stage(0, eA, oA);
    if (tix < 32) {                       // zero pads, both buffers
        const int b = tix >> 4, rj = (tix >> 2) & 3, pl = (tix >> 1) & 1;
        lds[b][rj][pl][(tix & 1) ? 129 : 0] = 0.f;
    }
    loadRows(oh0 + 2, eB, oB);            // round 1
    __syncthreads();

    for (int rr = 0; rr < NROUND - 1; rr += 2) {
        computeRound(rr, 0);
        stage(1, eB, oB);                              // round rr+1 -> buf1
        if (rr + 2 < NROUND) loadRows(oh0 - 2 + 4*(rr + 2), eA, oA);
        barrier_lgkm_only();
        computeRound(rr + 1, 1);
        if (rr + 2 < NROUND) {
            stage(0, eA, oA);                          // round rr+2 -> buf0
            if (rr + 3 < NROUND) loadRows(oh0 - 2 + 4*(rr + 3), eB, oB);
        }
        barrier_lgkm_only();
    }
    computeRound(NROUND - 1, 0);          // round 16 (even -> buf0)
}

extern "C" void kernel_launch(void* const* d_in, const int* in_sizes, int n_in,
                              void* d_out, int out_size, void* d_ws, size_t ws_size,
                              hipStream_t stream)
{
    const float* x  = (const float*)d_in[0];
    const float* k4 = (const float*)d_in[1];
    float* out      = (float*)d_out;

    dim3 grid(NBC, NSTRIP, 1);
    upsamp_fir_q4<<<grid, dim3(256), 0, stream>>>(x, k4, out);
}

// Round 9
// 261.672 us; speedup vs baseline: 1.5013x; 1.0133x over previous
//
#include <hip/hip_runtime.h>

// x: [16,128,128,128] fp32 ; pixel_shuffle(2) -> [16,32,256,256]
// 4x4 separable FIR (outer([1,3,3,1])/64), pad=2 -> out [16,32,257,257]
//
// R11: R5/R6's clean-write geometry with a decoupled staging pipeline.
// Write-amplification evidence (R7-R10): WRITE is clean (133-137MB) iff
// adjacent output rows are stored ~<=3Kcy apart (R0-R4 ~1.4K, R5/R6 ~3K);
// any longer cadence pays 1.57-1.77x at TCC->EA + RMW refetch, regardless
// of store instr shape (R8), stream count (R9), or block-coop (R10).
// => keep R5's store macro-pattern EXACTLY: grid (512,4), 256 thr, thread c
// owns col c, ONE row stored per barrier round.
// R5's residual: round wall 3216cy vs ~1600cy HBM pacing — the per-round
// chain ds_write -> barrier -> ds_read -> FMA -> store was serial.
// Fix: 4-slot LDS ring (slot = round&3). Round r: waves 0/1 stage row
// s_{r+2} (float2/lane, ds_write2) = TWO barriers ahead of its reader;
// register ring holds rows s_{r+2}..s_{r+4} (loads issued 2 rounds before
// ds_write, ~3Kcy vmcnt cover). Round-critical path collapses to
// barrier -> ds_read2(120cy) -> 7 FMA -> store. Load instrs /2, LDS write
// instrs /2; waves 2/3 compute-only. lgkm-only barrier (R6-proven) so
// loads/stores never drain at barriers.
constexpr int Hn = 128;
constexpr int Wn = 128;
constexpr int SH = 2 * Hn;   // 256 shuffled rows
constexpr int OH = SH + 1;   // 257
constexpr int OW = 257;
constexpr int HW = Hn * Wn;  // input plane stride
constexpr int TY = 65;       // output rows per block-strip
constexpr int NSTRIP = 4;    // 4*65 = 260 >= 257
constexpr int NBC = 16 * 32; // 512 (b,c) planes
constexpr int NIT = TY + 3;  // 68 rounds (rows staged per strip)

// Barrier that does NOT drain vmem (R6-proven): LDS ordering only.
__device__ __forceinline__ void barrier_lgkm_only() {
    asm volatile("s_waitcnt lgkmcnt(0)\n\ts_barrier" ::: "memory");
}

__global__ __launch_bounds__(256, 8) void upsamp_fir_ring(
    const float* __restrict__ x,
    const float* __restrict__ k4,
    float* __restrict__ out)
{
    const int tix = threadIdx.x;
    const int wid = tix >> 6;
    const int l   = tix & 63;
    const int bc  = blockIdx.x;
    const int oh0 = blockIdx.y * TY;
    const float* xp = x + (size_t)bc * 4 * HW;

    // Separable taps (flipped for true convolution), exact for this kernel.
    float fh[4], fv[4];
#pragma unroll
    for (int j = 0; j < 4; ++j) fh[j] = k4[j] + k4[4+j] + k4[8+j] + k4[12+j];
#pragma unroll
    for (int i = 0; i < 4; ++i) fv[i] = k4[4*i] + k4[4*i+1] + k4[4*i+2] + k4[4*i+3];
    const float t0 = fh[3], t1 = fh[2], t2 = fh[1], t3 = fh[0];
    const float g0 = fv[3], g1 = fv[2], g2 = fv[1], g3 = fv[0];

    // LDS ring: [slot][E/O][132]. B[1+k] = shuffled col 2k(+parity), data
    // [1..128], pads [0] and [129] zeroed once (never overwritten).
    __shared__ float lds[4][2][132];

    // Staging (waves 0/1 only): wave w loads plane 2*(s&1)+w of input row
    // s>>1, lane l covers dwords 2l,2l+1 (float2, 8B-aligned).
    auto qload = [&](int s) -> float2 {
        if ((unsigned)s >= (unsigned)SH) return make_float2(0.f, 0.f);
        const float* b = xp + (size_t)(2 * (s & 1) + wid) * HW
                            + (size_t)(s >> 1) * Wn + 2 * l;
        return *(const float2*)b;
    };
    auto qstage = [&](int slot, float2 v) {
        float* B = &lds[slot][wid][1 + 2 * l];
        B[0] = v.x; B[1] = v.y;            // ds_write2_b32
    };

    // Compute: thread owns output col c = tix (thread 255 also col 256).
    const int c    = tix;
    const int mi   = c >> 1;
    const int codd = c & 1;
    const bool edge = (tix == 255);
    float* const obase = out + (size_t)bc * OH * OW;

    float hp1 = 0, hp2 = 0, hp3 = 0;     // H(s_{r-1}), H(s_{r-2}), H(s_{r-3})
    float ep1 = 0, ep2 = 0, ep3 = 0;     // col-256 rolling (edge thread)

    auto compute = [&](int r, int slot) {
        const float* EB = &lds[slot][0][0];
        const float* OB = &lds[slot][1][0];
        // even c: P=EB+mi, Q=OB+mi ; odd c: P=OB+mi, Q=EB+mi+1
        const float* P = codd ? (OB + mi)     : (EB + mi);
        const float* Q = codd ? (EB + mi + 1) : (OB + mi);
        const float p0 = P[0], p1 = P[1];  // ds_read2_b32
        const float q0 = Q[0], q1 = Q[1];  // ds_read2_b32
        const float hn = t0*p0 + t1*q0 + t2*p1 + t3*q1;
        const float en = t0*q0 + t1*p1;    // col 256 (edge: E[254],O[255])
        if (r >= 3) {
            const int oh = oh0 + r - 3;
            if (oh < OH) {
                float* p = obase + (size_t)oh * OW;
                p[c] = g0*hp3 + g1*hp2 + g2*hp1 + g3*hn;   // clean cadence
                if (edge) p[256] = g0*ep3 + g1*ep2 + g2*ep1 + g3*en;
            }
        }
        hp3 = hp2; hp2 = hp1; hp1 = hn;
        ep3 = ep2; ep2 = ep1; ep1 = en;
    };

    // Round r: stage row s_{r+2} (from qw, loaded at round r-2) into slot
    // (r+2)&3; refill ql with row s_{r+4}; barrier; read slot r&3.
    // Hazards: writes slot (r+2)&3 vs concurrent reads r&3 / (r-1)&3 /
    // (r+... max skew 1 barrier -> distinct slots; write->read separated by
    // 2 barriers; write-after-read by 1 barrier. All safe.
    auto round = [&](int r, float2& qw, float2& ql) {
        if (wid < 2) {
            if (r + 2 < NIT) qstage((r + 2) & 3, qw);
            if (r + 4 < NIT) ql = qload(oh0 - 2 + r + 4);
        }
        barrier_lgkm_only();
        compute(r, r & 3);
    };

    // Prologue: slots 0,1 <- rows s_0,s_1; ring q2,q3 <- rows s_2,s_3.
    float2 q0v = make_float2(0.f, 0.f), q1v = q0v, q2v = q0v, q3v = q0v;
    if (wid < 2) {
        float2 t;
        t = qload(oh0 - 2); qstage(0, t);
        t = qload(oh0 - 1); qstage(1, t);
        q2v = qload(oh0);
        q3v = qload(oh0 + 1);
    }
    if (tix < 16)
        lds[tix & 3][(tix >> 2) & 1][(tix >> 3) ? 129 : 0] = 0.f;
    __syncthreads();   // once; drains prologue staging

    // NIT = 68 = 17 x 4: static ring indices via 4-round unrolled body.
    for (int mm = 0; mm < NIT; mm += 4) {
        round(mm + 0, q2v, q0v);   // consume s_{mm+2}, load s_{mm+4}
        round(mm + 1, q3v, q1v);
        round(mm + 2, q0v, q2v);
        round(mm + 3, q1v, q3v);
    }
}

extern "C" void kernel_launch(void* const* d_in, const int* in_sizes, int n_in,
                              void* d_out, int out_size, void* d_ws, size_t ws_size,
                              hipStream_t stream)
{
    const float* x  = (const float*)d_in[0];
    const float* k4 = (const float*)d_in[1];
    float* out      = (float*)d_out;

    dim3 grid(NBC, NSTRIP, 1);
    upsamp_fir_ring<<<grid, dim3(256), 0, stream>>>(x, k4, out);
}